// Round 1
// baseline (1194.826 us; speedup 1.0000x reference)
//
#include <hip/hip_runtime.h>

typedef unsigned short ush;
typedef unsigned int uint32;
typedef __attribute__((ext_vector_type(8))) __bf16 bf16x8;
typedef __attribute__((ext_vector_type(4))) float f32x4;

#define NBLK 64
#define NTHR 512
#define SENC 256
#define TDEC 512
#define HDIM 128
#define HSTR 136  // h_lds row stride in ushorts: 128 + 8 pad -> 2-way bank aliasing (free)

__device__ __forceinline__ float bf2f(ush u){
  uint32 v = ((uint32)u) << 16;
  return __builtin_bit_cast(float, v);
}
__device__ __forceinline__ ush f2bf(float f){
  uint32 u = __builtin_bit_cast(uint32, f);
  u = (u + 0x7FFFu + ((u >> 16) & 1u)) >> 16;  // RNE
  return (ush)u;
}
__device__ __forceinline__ float lo16f(uint32 w){ return __builtin_bit_cast(float, w << 16); }
__device__ __forceinline__ float hi16f(uint32 w){ return __builtin_bit_cast(float, w & 0xFFFF0000u); }

__device__ __forceinline__ float loadf(const void* p, int i, bool f32){
  return f32 ? ((const float*)p)[i] : bf2f(((const ush*)p)[i]);
}
__device__ __forceinline__ bf16x8 load8bf(const void* p, int i, bool f32){
  bf16x8 r;
  if (!f32){
    uint4 u = *reinterpret_cast<const uint4*>((const ush*)p + i);
    r = __builtin_bit_cast(bf16x8, u);
  } else {
    const float* fp = (const float*)p + i;
    #pragma unroll
    for (int j = 0; j < 8; ++j) r[j] = (__bf16)fp[j];
  }
  return r;
}
// NaN-free: exp(+inf)->inf, rcp(inf)->0; exp(-inf)->0
__device__ __forceinline__ float sigm(float x){
  return __builtin_amdgcn_rcpf(1.0f + __expf(-x));
}
__device__ __forceinline__ float tnh(float x){
  return 1.0f - 2.0f * __builtin_amdgcn_rcpf(__expf(2.0f * x) + 1.0f);
}

// One block = 16 batch rows, 8 waves. Wave w owns hidden cols [16w,16w+16).
// Per step: gates(16x512) = h(16x128) @ Whh^T via 16x16x32 bf16 MFMA,
// Whh fragments live in registers (loop-invariant), h double-buffered in LDS.
__global__ void __launch_bounds__(NTHR, 2)
lstm_kernel(const void* __restrict__ xg,  const void* __restrict__ wih,
            const void* __restrict__ whh, const void* __restrict__ bih,
            const void* __restrict__ bhh, const void* __restrict__ wfc,
            const void* __restrict__ bfc, void* __restrict__ outg)
{
  __shared__ __attribute__((aligned(16))) ush   x_lds[SENC * 32];      // [t][row*2+c] bf16
  __shared__ __attribute__((aligned(16))) ush   h_lds[2][16 * HSTR];   // [buf][row][j] bf16
  __shared__ __attribute__((aligned(16))) ush   xpred[2][32];          // [buf][row*2+o] bf16
  __shared__ __attribute__((aligned(16))) float pred_part[2][32][8];   // [buf][row*2+o][wave]

  const int tid   = threadIdx.x;
  const int lane  = tid & 63;
  const int wv    = tid >> 6;
  const int n     = lane & 15;   // MFMA: A-row m / B-col n / C-col
  const int q     = lane >> 4;   // quad
  const int gbase = wv << 4;     // this wave's hidden-col base
  const int blk   = blockIdx.x;

  // ---- runtime storage-dtype detection (bf16 vs f32) from w_hh bit patterns ----
  // For packed bf16, the low 16 bits of each u32 are a bf16 whose exponent
  // (bits 14:7) sits in ~[100,126] for N(0,0.088) data; for f32 those bits are
  // uniform-random mantissa bits (~20% hit the window).
  const uint32* wp = (const uint32*)whh;
  int cnt = 0;
  #pragma unroll
  for (int i = 0; i < 64; ++i){
    uint32 e = (wp[i] >> 7) & 0xFFu;
    cnt += (e >= 90u && e <= 140u) ? 1 : 0;
  }
  const bool isf32 = (cnt < 40);

  // zero initial h (buffer 0)
  for (int i = tid; i < 16 * HSTR; i += NTHR) h_lds[0][i] = 0;

  // stage this block's encoder inputs into LDS as bf16: [t][row*2+c]
  for (int i = tid; i < SENC * 32; i += NTHR){
    int t = i >> 5, rc = i & 31;
    int src = (blk * 16 + (rc >> 1)) * (SENC * 2) + t * 2 + (rc & 1);
    x_lds[i] = isf32 ? f2bf(((const float*)xg)[src]) : ((const ush*)xg)[src];
  }

  // ---- per-lane loop-invariant preloads ----
  float biasv[4], wih0v[4], wih1v[4];
  bf16x8 bfr[4][4];  // [gate p][K-chunk kk] B-fragment: Whh^T[k][g], k=kk*32+q*8+j, g=p*128+gbase+n
  #pragma unroll
  for (int p = 0; p < 4; ++p){
    int g = p * 128 + gbase + n;
    biasv[p] = loadf(bih, g, isf32) + loadf(bhh, g, isf32);
    wih0v[p] = loadf(wih, g * 2 + 0, isf32);
    wih1v[p] = loadf(wih, g * 2 + 1, isf32);
    #pragma unroll
    for (int kk = 0; kk < 4; ++kk)
      bfr[p][kk] = load8bf(whh, g * HDIM + kk * 32 + q * 8, isf32);
  }
  const float wfc0 = loadf(wfc, gbase + n, isf32);          // w_fc[0][j], j=gbase+n
  const float wfc1 = loadf(wfc, HDIM + gbase + n, isf32);   // w_fc[1][j]
  const float pbfc = loadf(bfc, (lane >> 4) & 1, isf32);

  float creg[4] = {0.f, 0.f, 0.f, 0.f};  // c for rows q*4+r, col gbase+n

  __syncthreads();

  #pragma unroll 1
  for (int s = 0; s < SENC + TDEC; ++s){
    const int cur = s & 1, nxt = cur ^ 1;

    // A fragments: h[m][k], m=n(lane&15), k=kk*32+q*8+j
    bf16x8 af[4];
    const ush* hb = &h_lds[cur][n * HSTR];
    #pragma unroll
    for (int kk = 0; kk < 4; ++kk)
      af[kk] = *reinterpret_cast<const bf16x8*>(hb + kk * 32 + q * 8);

    f32x4 acc[4];
    #pragma unroll
    for (int p = 0; p < 4; ++p){
      acc[p][0] = biasv[p]; acc[p][1] = biasv[p];
      acc[p][2] = biasv[p]; acc[p][3] = biasv[p];
    }
    #pragma unroll
    for (int kk = 0; kk < 4; ++kk){
      #pragma unroll
      for (int p = 0; p < 4; ++p)
        acc[p] = __builtin_amdgcn_mfma_f32_16x16x32_bf16(af[kk], bfr[p][kk], acc[p], 0, 0, 0);
    }

    // barrier1 (decode only): publishes xpred[cur] written by wave0 after
    // the previous step's barrier2 — overlapped with the MFMAs above.
    if (s > SENC) __syncthreads();

    // x input: encoder reads x_lds[t] (t=min(s,255) covers inp0=x[:,-1,:]),
    // decoder reads fed-back prediction.
    const ush* xsrc = (s <= SENC) ? &x_lds[(s < SENC ? s : SENC - 1) * 32]
                                  : &xpred[cur][0];
    uint4 xu = *reinterpret_cast<const uint4*>(xsrc + q * 8);
    float xa[4], xb[4];
    xa[0] = lo16f(xu.x); xb[0] = hi16f(xu.x);
    xa[1] = lo16f(xu.y); xb[1] = hi16f(xu.y);
    xa[2] = lo16f(xu.z); xb[2] = hi16f(xu.z);
    xa[3] = lo16f(xu.w); xb[3] = hi16f(xu.w);

    float hv[4];
    #pragma unroll
    for (int r = 0; r < 4; ++r){
      float iv = acc[0][r] + wih0v[0] * xa[r] + wih1v[0] * xb[r];
      float fv = acc[1][r] + wih0v[1] * xa[r] + wih1v[1] * xb[r];
      float gv = acc[2][r] + wih0v[2] * xa[r] + wih1v[2] * xb[r];
      float ov = acc[3][r] + wih0v[3] * xa[r] + wih1v[3] * xb[r];
      float si = sigm(iv), sf = sigm(fv), tg = tnh(gv), so = sigm(ov);
      creg[r] = sf * creg[r] + si * tg;
      hv[r]   = so * tnh(creg[r]);
      h_lds[nxt][(q * 4 + r) * HSTR + gbase + n] = f2bf(hv[r]);
    }

    // decoder: per-wave pred partials from registers (no LDS read of h),
    // reduced across the 16 n-lanes by shfl_xor.
    if (s >= SENC){
      float pr[8];  // [r][o]
      #pragma unroll
      for (int r = 0; r < 4; ++r){ pr[r * 2] = hv[r] * wfc0; pr[r * 2 + 1] = hv[r] * wfc1; }
      #pragma unroll
      for (int off = 1; off < 16; off <<= 1){
        #pragma unroll
        for (int k2 = 0; k2 < 8; ++k2) pr[k2] += __shfl_xor(pr[k2], off, 64);
      }
      if (n == 0){
        #pragma unroll
        for (int r = 0; r < 4; ++r){
          pred_part[nxt][(q * 4 + r) * 2 + 0][wv] = pr[r * 2];
          pred_part[nxt][(q * 4 + r) * 2 + 1][wv] = pr[r * 2 + 1];
        }
      }
    }

    __syncthreads();  // barrier2: publishes h_lds[nxt] (+ pred_part[nxt])

    // wave0 finalizes pred while other waves run ahead into the next step's
    // MFMA phase (they re-sync at barrier1).
    if (s >= SENC && wv == 0 && lane < 32){
      const int row = lane & 15, o = lane >> 4;
      const float4* pp = reinterpret_cast<const float4*>(&pred_part[nxt][row * 2 + o][0]);
      float4 a4 = pp[0], b4 = pp[1];
      float val = ((a4.x + a4.y) + (a4.z + a4.w)) + ((b4.x + b4.y) + (b4.z + b4.w)) + pbfc;
      xpred[nxt][row * 2 + o] = f2bf(val);
      int d  = s - SENC;
      int oi = ((blk * 16 + row) * TDEC + d) * 2 + o;
      if (isf32) ((float*)outg)[oi] = val;
      else       ((ush*)outg)[oi]   = f2bf(val);
    }
  }
}

extern "C" void kernel_launch(void* const* d_in, const int* in_sizes, int n_in,
                              void* d_out, int out_size, void* d_ws, size_t ws_size,
                              hipStream_t stream) {
  // inputs: x, w_ih, w_hh, b_ih, b_hh, w_fc, b_fc, target_length(=512, compile-time)
  lstm_kernel<<<dim3(NBLK), dim3(NTHR), 0, stream>>>(
      d_in[0], d_in[1], d_in[2], d_in[3], d_in[4], d_in[5], d_in[6], d_out);
}

// Round 3
// 910.029 us; speedup vs baseline: 1.3130x; 1.3130x over previous
//
#include <hip/hip_runtime.h>

typedef unsigned short ush;
typedef unsigned int uint32;
typedef __attribute__((ext_vector_type(8))) __bf16 bf16x8;
typedef __attribute__((ext_vector_type(4))) float f32x4;

#define NBLK 64
#define NTHR 512
#define SENC 256
#define TDEC 512
#define HDIM 128
#define HSTR 136   // h row stride (ush): 272B, 16B-aligned rows for ds_read_b128
#define PSTR 1032  // pred row stride (ush): 2064B, 16B-aligned rows for uint4 copy

#define LOG2E  1.4426950408889634f
#define LOG2E2 2.8853900817779268f

__device__ __forceinline__ float bf2f(ush u){
  uint32 v = ((uint32)u) << 16;
  return __builtin_bit_cast(float, v);
}
__device__ __forceinline__ ush f2bf(float f){
  uint32 u = __builtin_bit_cast(uint32, f);
  u = (u + 0x7FFFu + ((u >> 16) & 1u)) >> 16;  // RNE
  return (ush)u;
}
__device__ __forceinline__ float lo16f(uint32 w){ return __builtin_bit_cast(float, w << 16); }
__device__ __forceinline__ float hi16f(uint32 w){ return __builtin_bit_cast(float, w & 0xFFFF0000u); }

__device__ __forceinline__ float loadf(const void* p, int i, bool f32){
  return f32 ? ((const float*)p)[i] : bf2f(((const ush*)p)[i]);
}
// raw 8-elem bf16 fragment load: for bf16 inputs this is a BIT-EXACT copy of
// the harness weights (critical: zero weight-path quantization mismatch).
__device__ __forceinline__ bf16x8 load8bf(const void* p, int i, bool f32){
  bf16x8 r;
  if (!f32){
    uint4 u = *reinterpret_cast<const uint4*>((const ush*)p + i);
    r = __builtin_bit_cast(bf16x8, u);
  } else {
    const float* fp = (const float*)p + i;
    #pragma unroll
    for (int j = 0; j < 8; ++j) r[j] = (__bf16)fp[j];
  }
  return r;
}
// NaN-free activations; log2e applied inside (weights stay exact)
__device__ __forceinline__ float sigm(float x){
  return __builtin_amdgcn_rcpf(1.0f + __builtin_amdgcn_exp2f(-x * LOG2E));
}
__device__ __forceinline__ float tnh(float x){
  return 1.0f - 2.0f * __builtin_amdgcn_rcpf(__builtin_amdgcn_exp2f(x * LOG2E2) + 1.0f);
}

// One block = 16 batch rows, 8 waves; wave w owns hidden cols [16w,16w+16).
// Per step: gates(16x512) = h(16x128) @ Whh^T via 16x16x32 bf16 MFMA with
// register-resident EXACT bf16 weights; ONE barrier per step.
// Decoder feedback: every wave computes the pred tile (4 extra MFMAs on the
// same A-frags, B = Wfc^T zero-padded), broadcasts pred[row][0..1] via shfl,
// and applies gates += wih * pred in f32 (matches np ref's unrounded pred).
// Preds buffered in LDS; ONE coalesced global write after the loop
// (no vmcnt(0) drain before any in-loop barrier).
__global__ void __launch_bounds__(NTHR, 2)
lstm_kernel(const void* __restrict__ xg,  const void* __restrict__ wih,
            const void* __restrict__ whh, const void* __restrict__ bih,
            const void* __restrict__ bhh, const void* __restrict__ wfc,
            const void* __restrict__ bfc, void* __restrict__ outg)
{
  __shared__ __attribute__((aligned(16))) ush x_lds[SENC * 32];     // [t][row*2+c]
  __shared__ __attribute__((aligned(16))) ush h_lds[2][16 * HSTR];  // [buf][row][j]
  __shared__ __attribute__((aligned(16))) ush pred_lds[16][PSTR];   // [row][d*2+o]

  const int tid   = threadIdx.x;
  const int lane  = tid & 63;
  const int wv    = tid >> 6;
  const int n     = lane & 15;   // MFMA: A-row m / B-col n / C-col
  const int q     = lane >> 4;   // quad
  const int gbase = wv << 4;
  const int blk   = blockIdx.x;

  // runtime storage-dtype detection (bf16 vs f32) from w_hh bit patterns
  const uint32* wp = (const uint32*)whh;
  int cnt = 0;
  #pragma unroll
  for (int i = 0; i < 64; ++i){
    uint32 e = (wp[i] >> 7) & 0xFFu;
    cnt += (e >= 90u && e <= 140u) ? 1 : 0;
  }
  const bool isf32 = (cnt < 40);

  for (int i = tid; i < 16 * HSTR; i += NTHR) h_lds[0][i] = 0;

  for (int i = tid; i < SENC * 32; i += NTHR){
    int t = i >> 5, rc = i & 31;
    int src = (blk * 16 + (rc >> 1)) * (SENC * 2) + t * 2 + (rc & 1);
    x_lds[i] = isf32 ? f2bf(((const float*)xg)[src]) : ((const ush*)xg)[src];
  }

  // ---- loop-invariant preloads: weights RAW (bit-exact for bf16 inputs) ----
  float biasv[4], wih0v[4], wih1v[4];
  bf16x8 bfr[4][4];  // [gate p][kk]: B[k][g]=Whh[g][k], k=kk*32+q*8+j, g=p*128+gbase+n
  #pragma unroll
  for (int p = 0; p < 4; ++p){
    int g = p * 128 + gbase + n;
    biasv[p] = loadf(bih, g, isf32) + loadf(bhh, g, isf32);
    wih0v[p] = loadf(wih, g * 2 + 0, isf32);
    wih1v[p] = loadf(wih, g * 2 + 1, isf32);
    #pragma unroll
    for (int kk = 0; kk < 4; ++kk)
      bfr[p][kk] = load8bf(whh, g * HDIM + kk * 32 + q * 8, isf32);
  }
  // pred tile B-frag: B[k][n] = wfc[n][k] for n<2, else 0
  bf16x8 wfcfr[4];
  #pragma unroll
  for (int kk = 0; kk < 4; ++kk){
    #pragma unroll
    for (int j = 0; j < 8; ++j){
      int k = kk * 32 + q * 8 + j;
      float v = (n < 2) ? loadf(wfc, n * HDIM + k, isf32) : 0.0f;
      wfcfr[kk][j] = __builtin_bit_cast(__bf16, f2bf(v));
    }
  }
  const float pbfc = (n < 2) ? loadf(bfc, n, isf32) : 0.0f;

  float creg[4] = {0.f, 0.f, 0.f, 0.f};  // c for rows q*4+r, col gbase+n

  __syncthreads();

  #pragma unroll 1
  for (int s = 0; s < SENC + TDEC; ++s){
    const int cur = s & 1, nxt = cur ^ 1;
    const bool dec = (s > SENC);

    // acc init: bias + x-path (x doesn't depend on h -> off the critical path)
    f32x4 acc[4];
    if (!dec){
      const ush* xsrc = &x_lds[(s < SENC ? s : SENC - 1) * 32];
      uint4 xu = *reinterpret_cast<const uint4*>(xsrc + q * 8);
      float xa[4], xb[4];
      xa[0] = lo16f(xu.x); xb[0] = hi16f(xu.x);
      xa[1] = lo16f(xu.y); xb[1] = hi16f(xu.y);
      xa[2] = lo16f(xu.z); xb[2] = hi16f(xu.z);
      xa[3] = lo16f(xu.w); xb[3] = hi16f(xu.w);
      #pragma unroll
      for (int p = 0; p < 4; ++p){
        #pragma unroll
        for (int r = 0; r < 4; ++r)
          acc[p][r] = biasv[p] + wih0v[p] * xa[r] + wih1v[p] * xb[r];
      }
    } else {
      #pragma unroll
      for (int p = 0; p < 4; ++p){
        acc[p][0] = biasv[p]; acc[p][1] = biasv[p];
        acc[p][2] = biasv[p]; acc[p][3] = biasv[p];
      }
    }

    // A fragments: h[m][k], m=n, k=kk*32+q*8+j
    bf16x8 af[4];
    const ush* hb = &h_lds[cur][n * HSTR];
    #pragma unroll
    for (int kk = 0; kk < 4; ++kk)
      af[kk] = *reinterpret_cast<const bf16x8*>(hb + kk * 32 + q * 8);

    // pred tile first (shortest path to the shfl consumers)
    f32x4 a4;
    if (dec){
      a4[0] = pbfc; a4[1] = pbfc; a4[2] = pbfc; a4[3] = pbfc;
      #pragma unroll
      for (int kk = 0; kk < 4; ++kk)
        a4 = __builtin_amdgcn_mfma_f32_16x16x32_bf16(af[kk], wfcfr[kk], a4, 0, 0, 0);
    }
    #pragma unroll
    for (int kk = 0; kk < 4; ++kk){
      #pragma unroll
      for (int p = 0; p < 4; ++p)
        acc[p] = __builtin_amdgcn_mfma_f32_16x16x32_bf16(af[kk], bfr[p][kk], acc[p], 0, 0, 0);
    }

    if (dec){
      // broadcast pred[4q+r][0..1] from lanes 16q+0 / 16q+1; apply rank-2
      // x-path in f32 (pred unrounded -> matches reference numerics)
      const int l0 = lane & 48;
      #pragma unroll
      for (int r = 0; r < 4; ++r){
        float p0 = __shfl(a4[r], l0, 64);
        float p1 = __shfl(a4[r], l0 | 1, 64);
        #pragma unroll
        for (int p = 0; p < 4; ++p)
          acc[p][r] += wih0v[p] * p0 + wih1v[p] * p1;
      }
    }

    #pragma unroll
    for (int r = 0; r < 4; ++r){
      float si = sigm(acc[0][r]), sf = sigm(acc[1][r]);
      float tg = tnh(acc[2][r]),  so = sigm(acc[3][r]);
      creg[r] = sf * creg[r] + si * tg;
      float hv = so * tnh(creg[r]);
      h_lds[nxt][(q * 4 + r) * HSTR + gbase + n] = f2bf(hv);
    }

    // stash pred_{s-1-SENC} in LDS (wave0, 8 lanes) — read only after the loop
    if (dec && wv == 0 && n < 2){
      int d = s - SENC - 1;
      #pragma unroll
      for (int r = 0; r < 4; ++r)
        pred_lds[q * 4 + r][d * 2 + n] = f2bf(a4[r]);
    }

    __syncthreads();  // publishes h_lds[nxt]; LDS-only drain (no vmcnt)
  }

  // epilogue: pred_511 from h_767 (in h_lds[0])
  if (wv == 0){
    bf16x8 af[4];
    const ush* hb = &h_lds[(SENC + TDEC) & 1][n * HSTR];
    #pragma unroll
    for (int kk = 0; kk < 4; ++kk)
      af[kk] = *reinterpret_cast<const bf16x8*>(hb + kk * 32 + q * 8);
    f32x4 a4;
    a4[0] = pbfc; a4[1] = pbfc; a4[2] = pbfc; a4[3] = pbfc;
    #pragma unroll
    for (int kk = 0; kk < 4; ++kk)
      a4 = __builtin_amdgcn_mfma_f32_16x16x32_bf16(af[kk], wfcfr[kk], a4, 0, 0, 0);
    if (n < 2){
      #pragma unroll
      for (int r = 0; r < 4; ++r)
        pred_lds[q * 4 + r][(TDEC - 1) * 2 + n] = f2bf(a4[r]);
    }
  }
  __syncthreads();

  // bulk coalesced output write: 16 rows x 1024 ush -> one chunk per thread
  if (!isf32){
    const int row = tid >> 5, ch = tid & 31;  // 32 chunks x 32 ush per row
    const uint4* src = reinterpret_cast<const uint4*>(&pred_lds[row][ch * 32]);
    uint4* dst = reinterpret_cast<uint4*>((ush*)outg + (blk * 16 + row) * (TDEC * 2) + ch * 32);
    uint4 v0 = src[0], v1 = src[1], v2 = src[2], v3 = src[3];
    dst[0] = v0; dst[1] = v1; dst[2] = v2; dst[3] = v3;
  } else {
    for (int i = tid; i < 16 * TDEC * 2; i += NTHR){
      int row = i >> 10, c = i & 1023;
      ((float*)outg)[(blk * 16 + row) * (TDEC * 2) + c] = bf2f(pred_lds[row][c]);
    }
  }
}

extern "C" void kernel_launch(void* const* d_in, const int* in_sizes, int n_in,
                              void* d_out, int out_size, void* d_ws, size_t ws_size,
                              hipStream_t stream) {
  lstm_kernel<<<dim3(NBLK), dim3(NTHR), 0, stream>>>(
      d_in[0], d_in[1], d_in[2], d_in[3], d_in[4], d_in[5], d_in[6], d_out);
}

// Round 4
// 471.495 us; speedup vs baseline: 2.5341x; 1.9301x over previous
//
#include <hip/hip_runtime.h>

typedef unsigned short ush;
typedef unsigned int uint32;
typedef __attribute__((ext_vector_type(8))) __bf16 bf16x8;
typedef __attribute__((ext_vector_type(4))) float f32x4;

#define NBLK 256
#define RB   4     // batch rows per block
#define NTHR 512
#define SENC 256
#define TDEC 512
#define HDIM 128
// h row stride (ush): 144 = 72 dw; replicated A-reads (4 rows x 4 q-offsets,
// 16B each) start at dw 4*(18r+q) == 4*((2r+q)&7) mod 32 -> each bank-group
// covered exactly 2x (2-way = free, m136).
#define HSTR 144
#define XSTR 520   // x row stride (ush): 260 dw -> rows on distinct banks
#define PSTR 1024  // pred row stride (ush), 16B-aligned rows

#define LOG2E  1.4426950408889634f
#define LOG2E2 2.8853900817779268f

__device__ __forceinline__ float bf2f(ush u){
  uint32 v = ((uint32)u) << 16;
  return __builtin_bit_cast(float, v);
}
__device__ __forceinline__ ush f2bf(float f){
  uint32 u = __builtin_bit_cast(uint32, f);
  u = (u + 0x7FFFu + ((u >> 16) & 1u)) >> 16;  // RNE
  return (ush)u;
}
__device__ __forceinline__ float lo16f(uint32 w){ return __builtin_bit_cast(float, w << 16); }
__device__ __forceinline__ float hi16f(uint32 w){ return __builtin_bit_cast(float, w & 0xFFFF0000u); }

__device__ __forceinline__ float loadf(const void* p, int i, bool f32){
  return f32 ? ((const float*)p)[i] : bf2f(((const ush*)p)[i]);
}
// raw bf16 fragment load: bit-exact copy of harness weights for bf16 inputs
__device__ __forceinline__ bf16x8 load8bf(const void* p, int i, bool f32){
  bf16x8 r;
  if (!f32){
    uint4 u = *reinterpret_cast<const uint4*>((const ush*)p + i);
    r = __builtin_bit_cast(bf16x8, u);
  } else {
    const float* fp = (const float*)p + i;
    #pragma unroll
    for (int j = 0; j < 8; ++j) r[j] = (__bf16)fp[j];
  }
  return r;
}
__device__ __forceinline__ float sigm(float x){
  return __builtin_amdgcn_rcpf(1.0f + __builtin_amdgcn_exp2f(-x * LOG2E));
}
__device__ __forceinline__ float tnh(float x){
  return 1.0f - 2.0f * __builtin_amdgcn_rcpf(__builtin_amdgcn_exp2f(x * LOG2E2) + 1.0f);
}
// pick element q (q = lane>>4) out of a C-fragment
__device__ __forceinline__ float selq(f32x4 v, int q){
  float s01 = (q & 1) ? v[1] : v[0];
  float s23 = (q & 1) ? v[3] : v[2];
  return (q & 2) ? s23 : s01;
}

// 256 blocks x 4 batch rows -> all 256 CUs active. 8 waves/block; wave w owns
// hidden cols [16w,16w+16). A-ROW REPLICATION: A[m] = h[m&3] so the MFMA
// C-tile holds gates[row r][col n] in reg r of EVERY lane (n,q). Lane (n,q)
// selects r=q (3 cndmasks/gate) and processes exactly one (row,col) element:
// 10 transcendentals/lane/step instead of 40, no cross-lane redistribution.
// MFMA values bit-identical to the round-3 kernel; weights raw bf16 (exact).
// Decoder feedback (pred = h@Wfc^T + bfc) = 4 extra MFMAs on the same
// A-frags, selected + 2 shfl broadcasts, applied as f32 rank-2 update.
// Preds buffered in LDS; one coalesced global write at the end.
__global__ void __launch_bounds__(NTHR, 2)
lstm_kernel(const void* __restrict__ xg,  const void* __restrict__ wih,
            const void* __restrict__ whh, const void* __restrict__ bih,
            const void* __restrict__ bhh, const void* __restrict__ wfc,
            const void* __restrict__ bfc, void* __restrict__ outg)
{
  __shared__ __attribute__((aligned(16))) ush x_lds[RB * XSTR];      // [row][t*2+c]
  __shared__ __attribute__((aligned(16))) ush h_lds[2][RB * HSTR];   // [buf][row][j]
  __shared__ __attribute__((aligned(16))) ush pred_lds[RB][PSTR];    // [row][d*2+o]

  const int tid   = threadIdx.x;
  const int lane  = tid & 63;
  const int wv    = tid >> 6;
  const int n     = lane & 15;   // MFMA col index within tile
  const int q     = lane >> 4;   // quad; this lane's batch row
  const int gbase = wv << 4;
  const int blk   = blockIdx.x;

  // runtime storage-dtype detection (bf16 vs f32) from w_hh bit patterns
  const uint32* wp = (const uint32*)whh;
  int cnt = 0;
  #pragma unroll
  for (int i = 0; i < 64; ++i){
    uint32 e = (wp[i] >> 7) & 0xFFu;
    cnt += (e >= 90u && e <= 140u) ? 1 : 0;
  }
  const bool isf32 = (cnt < 40);

  for (int i = tid; i < 2 * RB * HSTR; i += NTHR) h_lds[0][i] = 0;  // both bufs

  // stage this block's 4 encoder rows into LDS as bf16: [row][t*2+c]
  if (!isf32){
    if (tid < 256){
      int row = tid >> 6, c = (tid & 63) * 8;
      uint4 v = *reinterpret_cast<const uint4*>((const ush*)xg + (blk * RB + row) * (SENC * 2) + c);
      *reinterpret_cast<uint4*>(&x_lds[row * XSTR + c]) = v;
    }
  } else {
    for (int i = tid; i < RB * SENC * 2; i += NTHR){
      int row = i >> 9, c = i & 511;
      x_lds[row * XSTR + c] = f2bf(((const float*)xg)[(blk * RB + row) * (SENC * 2) + c]);
    }
  }

  // ---- loop-invariant preloads: weights RAW (bit-exact for bf16) ----
  float biasv[4], wih0v[4], wih1v[4];
  bf16x8 bfr[4][4];  // [gate p][kk]: B[k][g]=Whh[g][k], k=kk*32+q*8+j, g=p*128+gbase+n
  #pragma unroll
  for (int p = 0; p < 4; ++p){
    int g = p * 128 + gbase + n;
    biasv[p] = loadf(bih, g, isf32) + loadf(bhh, g, isf32);
    wih0v[p] = loadf(wih, g * 2 + 0, isf32);
    wih1v[p] = loadf(wih, g * 2 + 1, isf32);
    #pragma unroll
    for (int kk = 0; kk < 4; ++kk)
      bfr[p][kk] = load8bf(whh, g * HDIM + kk * 32 + q * 8, isf32);
  }
  // pred tile B-frag: B[k][n] = wfc[n][k] for n<2, else 0
  bf16x8 wfcfr[4];
  #pragma unroll
  for (int kk = 0; kk < 4; ++kk){
    #pragma unroll
    for (int j = 0; j < 8; ++j){
      int k = kk * 32 + q * 8 + j;
      float v = (n < 2) ? loadf(wfc, n * HDIM + k, isf32) : 0.0f;
      wfcfr[kk][j] = __builtin_bit_cast(__bf16, f2bf(v));
    }
  }
  const float pbfc = (n < 2) ? loadf(bfc, n, isf32) : 0.0f;

  float cc = 0.0f;                 // c-state for (row q, col gbase+n)
  const int l0 = lane & 48;        // lane (0,q)

  __syncthreads();

  #pragma unroll 1
  for (int s = 0; s < SENC + TDEC; ++s){
    const int cur = s & 1, nxt = cur ^ 1;
    const bool dec = (s > SENC);

    // A fragments, row-replicated: lane m=n reads h[m&3][kk*32+q*8 ..]
    bf16x8 af[4];
    const ush* hb = &h_lds[cur][(n & 3) * HSTR];
    #pragma unroll
    for (int kk = 0; kk < 4; ++kk)
      af[kk] = *reinterpret_cast<const bf16x8*>(hb + kk * 32 + q * 8);

    f32x4 acc[4];
    #pragma unroll
    for (int p = 0; p < 4; ++p){
      acc[p][0] = biasv[p]; acc[p][1] = biasv[p];
      acc[p][2] = biasv[p]; acc[p][3] = biasv[p];
    }
    f32x4 a4;
    if (dec){
      a4[0] = pbfc; a4[1] = pbfc; a4[2] = pbfc; a4[3] = pbfc;
      #pragma unroll
      for (int kk = 0; kk < 4; ++kk)
        a4 = __builtin_amdgcn_mfma_f32_16x16x32_bf16(af[kk], wfcfr[kk], a4, 0, 0, 0);
    }
    #pragma unroll
    for (int kk = 0; kk < 4; ++kk){
      #pragma unroll
      for (int p = 0; p < 4; ++p)
        acc[p] = __builtin_amdgcn_mfma_f32_16x16x32_bf16(af[kk], bfr[p][kk], acc[p], 0, 0, 0);
    }

    // this lane's row-q gate pre-activations
    float g0 = selq(acc[0], q), g1 = selq(acc[1], q);
    float g2 = selq(acc[2], q), g3 = selq(acc[3], q);

    float pv = 0.0f;
    if (dec){
      // pred[q][n] (n<2 valid); broadcast cols 0,1 from lanes (0,q),(1,q)
      pv = selq(a4, q);
      float p0 = __shfl(pv, l0, 64);
      float p1 = __shfl(pv, l0 | 1, 64);
      g0 += wih0v[0] * p0 + wih1v[0] * p1;
      g1 += wih0v[1] * p0 + wih1v[1] * p1;
      g2 += wih0v[2] * p0 + wih1v[2] * p1;
      g3 += wih0v[3] * p0 + wih1v[3] * p1;
    } else {
      // encoder (and first decode cell: inp0 = x[:,-1,:])
      int t = (s < SENC) ? s : SENC - 1;
      uint32 xw = *reinterpret_cast<const uint32*>(&x_lds[q * XSTR + t * 2]);
      float xa = lo16f(xw), xb = hi16f(xw);
      g0 += wih0v[0] * xa + wih1v[0] * xb;
      g1 += wih0v[1] * xa + wih1v[1] * xb;
      g2 += wih0v[2] * xa + wih1v[2] * xb;
      g3 += wih0v[3] * xa + wih1v[3] * xb;
    }

    float si = sigm(g0), sf = sigm(g1), tg = tnh(g2), so = sigm(g3);
    cc = sf * cc + si * tg;
    float hv = so * tnh(cc);
    h_lds[nxt][q * HSTR + gbase + n] = f2bf(hv);

    // stash pred_{s-1-SENC}: lanes (n<2, q) of wave0 hold pred[q][n] in pv
    if (dec && wv == 0 && n < 2){
      int d = s - SENC - 1;
      pred_lds[q][d * 2 + n] = f2bf(pv);
    }

    __syncthreads();  // publishes h_lds[nxt]; LDS-only drain
  }

  // epilogue: pred_511 from h_767 (in h_lds[0])
  if (wv == 0){
    bf16x8 af[4];
    const ush* hb = &h_lds[(SENC + TDEC) & 1][(n & 3) * HSTR];
    #pragma unroll
    for (int kk = 0; kk < 4; ++kk)
      af[kk] = *reinterpret_cast<const bf16x8*>(hb + kk * 32 + q * 8);
    f32x4 a4;
    a4[0] = pbfc; a4[1] = pbfc; a4[2] = pbfc; a4[3] = pbfc;
    #pragma unroll
    for (int kk = 0; kk < 4; ++kk)
      a4 = __builtin_amdgcn_mfma_f32_16x16x32_bf16(af[kk], wfcfr[kk], a4, 0, 0, 0);
    if (n < 2)
      pred_lds[q][(TDEC - 1) * 2 + n] = f2bf(selq(a4, q));
  }
  __syncthreads();

  // bulk coalesced output write: 4 rows x 1024 ush per block
  if (!isf32){
    int row = tid >> 7, c = (tid & 127) * 8;  // 512 threads x uint4
    uint4 v = *reinterpret_cast<const uint4*>(&pred_lds[row][c]);
    *reinterpret_cast<uint4*>((ush*)outg + (blk * RB + row) * (TDEC * 2) + c) = v;
  } else {
    for (int i = tid; i < RB * TDEC * 2; i += NTHR){
      int row = i >> 10, c = i & 1023;
      ((float*)outg)[(blk * RB + row) * (TDEC * 2) + c] = bf2f(pred_lds[row][c]);
    }
  }
}

extern "C" void kernel_launch(void* const* d_in, const int* in_sizes, int n_in,
                              void* d_out, int out_size, void* d_ws, size_t ws_size,
                              hipStream_t stream) {
  lstm_kernel<<<dim3(NBLK), dim3(NTHR), 0, stream>>>(
      d_in[0], d_in[1], d_in[2], d_in[3], d_in[4], d_in[5], d_in[6], d_out);
}

// Round 5
// 467.238 us; speedup vs baseline: 2.5572x; 1.0091x over previous
//
#include <hip/hip_runtime.h>

typedef unsigned short ush;
typedef unsigned int uint32;
typedef __attribute__((ext_vector_type(8))) __bf16 bf16x8;
typedef __attribute__((ext_vector_type(4))) float f32x4;

#define NBLK 256
#define RB   4     // batch rows per block
#define NTHR 512
#define SENC 256
#define TDEC 512
#define HDIM 128
#define HSTR 144   // h row stride (ush): 72 dw ≡ 8 mod 32 -> replicated reads/writes 2-way (free)
#define XSTR 520   // x row stride (ush)
#define PSTR 1024  // pred row stride (ush)

#define LOG2E  1.4426950408889634f
#define LOG2E2 2.8853900817779268f

__device__ __forceinline__ float bf2f(ush u){
  uint32 v = ((uint32)u) << 16;
  return __builtin_bit_cast(float, v);
}
__device__ __forceinline__ ush f2bf(float f){            // RNE
  uint32 u = __builtin_bit_cast(uint32, f);
  u = (u + 0x7FFFu + ((u >> 16) & 1u)) >> 16;
  return (ush)u;
}
__device__ __forceinline__ float lo16f(uint32 w){ return __builtin_bit_cast(float, w << 16); }
__device__ __forceinline__ float hi16f(uint32 w){ return __builtin_bit_cast(float, w & 0xFFFF0000u); }

__device__ __forceinline__ float loadf(const void* p, int i, bool f32){
  return f32 ? ((const float*)p)[i] : bf2f(((const ush*)p)[i]);
}
// raw bf16 fragment load: bit-exact copy of harness weights for bf16 inputs
__device__ __forceinline__ bf16x8 load8bf(const void* p, int i, bool f32){
  bf16x8 r;
  if (!f32){
    uint4 u = *reinterpret_cast<const uint4*>((const ush*)p + i);
    r = __builtin_bit_cast(bf16x8, u);
  } else {
    const float* fp = (const float*)p + i;
    #pragma unroll
    for (int j = 0; j < 8; ++j) r[j] = (__bf16)fp[j];
  }
  return r;
}
__device__ __forceinline__ float sigm(float x){
  return __builtin_amdgcn_rcpf(1.0f + __builtin_amdgcn_exp2f(-x * LOG2E));
}
__device__ __forceinline__ float tnh(float x){
  return 1.0f - 2.0f * __builtin_amdgcn_rcpf(__builtin_amdgcn_exp2f(x * LOG2E2) + 1.0f);
}

// 256 blocks x 4 batch rows, 8 waves/block; wave w owns hidden cols [16w,16w+16).
// A-ROW REPLICATION (v2): A[m] = h[m>>2] so C[4q+r][n] = gates[q][n] for ALL r
// -> lane (n,q) reads acc[p][0] directly: ZERO select cndmasks.
// Bias rides in as the C operand of the first MFMA of each chain (bit-exact
// vs init-then-accumulate): ZERO acc-init movs.
// Decoder feedback = 4 extra MFMAs (B = Wfc^T zero-padded) + 2 shfl
// broadcasts + f32 rank-2 update (pred unrounded, matches np reference).
// Encoder and decoder are separate branchless loops; ONE barrier per step.
// All MFMA element values bit-identical to the round-4 kernel.
__global__ void __launch_bounds__(NTHR, 2)
lstm_kernel(const void* __restrict__ xg,  const void* __restrict__ wih,
            const void* __restrict__ whh, const void* __restrict__ bih,
            const void* __restrict__ bhh, const void* __restrict__ wfc,
            const void* __restrict__ bfc, void* __restrict__ outg)
{
  __shared__ __attribute__((aligned(16))) ush x_lds[RB * XSTR];      // [row][t*2+c]
  __shared__ __attribute__((aligned(16))) ush h_lds[2][RB * HSTR];   // [buf][row][j]
  __shared__ __attribute__((aligned(16))) ush pred_lds[RB][PSTR];    // [row][d*2+o]

  const int tid   = threadIdx.x;
  const int lane  = tid & 63;
  const int wv    = tid >> 6;
  const int n     = lane & 15;   // MFMA col index within tile (= A-row m)
  const int q     = lane >> 4;   // quad; this lane's batch row
  const int gbase = wv << 4;
  const int blk   = blockIdx.x;

  // runtime storage-dtype detection (bf16 vs f32) from w_hh bit patterns
  const uint32* wp = (const uint32*)whh;
  int cnt = 0;
  #pragma unroll
  for (int i = 0; i < 64; ++i){
    uint32 e = (wp[i] >> 7) & 0xFFu;
    cnt += (e >= 90u && e <= 140u) ? 1 : 0;
  }
  const bool isf32 = (cnt < 40);

  for (int i = tid; i < 2 * RB * HSTR; i += NTHR) h_lds[0][i] = 0;  // both bufs

  // stage this block's 4 encoder rows into LDS as bf16: [row][t*2+c]
  if (!isf32){
    if (tid < 256){
      int row = tid >> 6, c = (tid & 63) * 8;
      uint4 v = *reinterpret_cast<const uint4*>((const ush*)xg + (blk * RB + row) * (SENC * 2) + c);
      *reinterpret_cast<uint4*>(&x_lds[row * XSTR + c]) = v;
    }
  } else {
    for (int i = tid; i < RB * SENC * 2; i += NTHR){
      int row = i >> 9, c = i & 511;
      x_lds[row * XSTR + c] = f2bf(((const float*)xg)[(blk * RB + row) * (SENC * 2) + c]);
    }
  }

  // ---- loop-invariant preloads: weights RAW (bit-exact for bf16) ----
  float wih0v[4], wih1v[4];
  f32x4 biasC[4];    // broadcast bias, used as C operand of first MFMA
  bf16x8 bfr[4][4];  // [gate p][kk]: B[k][g]=Whh[g][k], k=kk*32+q*8+j, g=p*128+gbase+n
  #pragma unroll
  for (int p = 0; p < 4; ++p){
    int g = p * 128 + gbase + n;
    float b = loadf(bih, g, isf32) + loadf(bhh, g, isf32);
    biasC[p][0] = b; biasC[p][1] = b; biasC[p][2] = b; biasC[p][3] = b;
    wih0v[p] = loadf(wih, g * 2 + 0, isf32);
    wih1v[p] = loadf(wih, g * 2 + 1, isf32);
    #pragma unroll
    for (int kk = 0; kk < 4; ++kk)
      bfr[p][kk] = load8bf(whh, g * HDIM + kk * 32 + q * 8, isf32);
  }
  // pred tile B-frag: B[k][n] = wfc[n][k] for n<2, else 0; bias as C operand
  bf16x8 wfcfr[4];
  #pragma unroll
  for (int kk = 0; kk < 4; ++kk){
    #pragma unroll
    for (int j = 0; j < 8; ++j){
      int k = kk * 32 + q * 8 + j;
      float v = (n < 2) ? loadf(wfc, n * HDIM + k, isf32) : 0.0f;
      wfcfr[kk][j] = __builtin_bit_cast(__bf16, f2bf(v));
    }
  }
  f32x4 pbfcC;
  {
    float pb = (n < 2) ? loadf(bfc, n, isf32) : 0.0f;
    pbfcC[0] = pb; pbfcC[1] = pb; pbfcC[2] = pb; pbfcC[3] = pb;
  }

  float cc = 0.0f;                   // c-state for (row q, col gbase+n)
  const int l0    = lane & 48;       // lane (0,q)
  const int arow  = (n >> 2) * HSTR; // replicated A-row base: A[m]=h[m>>2]
  const int hwofs = q * HSTR + gbase + n;  // this lane's h-write offset
  int cur = 0;

  __syncthreads();

  // ---------------- encoder (+ first decode cell at s==SENC) ----------------
  #pragma unroll 1
  for (int s = 0; s <= SENC; ++s){
    const ush* hb = &h_lds[cur][arow];
    bf16x8 af[4];
    #pragma unroll
    for (int kk = 0; kk < 4; ++kk)
      af[kk] = *reinterpret_cast<const bf16x8*>(hb + kk * 32 + q * 8);

    f32x4 acc[4];
    #pragma unroll
    for (int p = 0; p < 4; ++p)
      acc[p] = __builtin_amdgcn_mfma_f32_16x16x32_bf16(af[0], bfr[p][0], biasC[p], 0, 0, 0);
    #pragma unroll
    for (int kk = 1; kk < 4; ++kk){
      #pragma unroll
      for (int p = 0; p < 4; ++p)
        acc[p] = __builtin_amdgcn_mfma_f32_16x16x32_bf16(af[kk], bfr[p][kk], acc[p], 0, 0, 0);
    }

    int t = (s < SENC) ? s : SENC - 1;   // s==SENC: inp0 = x[:,-1,:]
    uint32 xw = *reinterpret_cast<const uint32*>(&x_lds[q * XSTR + t * 2]);
    float xa = lo16f(xw), xb = hi16f(xw);

    float g0 = acc[0][0] + wih0v[0] * xa + wih1v[0] * xb;
    float g1 = acc[1][0] + wih0v[1] * xa + wih1v[1] * xb;
    float g2 = acc[2][0] + wih0v[2] * xa + wih1v[2] * xb;
    float g3 = acc[3][0] + wih0v[3] * xa + wih1v[3] * xb;

    float si = sigm(g0), sf = sigm(g1), tg = tnh(g2), so = sigm(g3);
    cc = sf * cc + si * tg;
    float hv = so * tnh(cc);
    h_lds[cur ^ 1][hwofs] = f2bf(hv);

    __syncthreads();
    cur ^= 1;
  }

  // ---------------- decoder: pure h-recurrence + pred feedback --------------
  #pragma unroll 1
  for (int d = 0; d < TDEC - 1; ++d){
    const ush* hb = &h_lds[cur][arow];
    bf16x8 af[4];
    #pragma unroll
    for (int kk = 0; kk < 4; ++kk)
      af[kk] = *reinterpret_cast<const bf16x8*>(hb + kk * 32 + q * 8);

    // pred_d = h @ wfc^T + bfc (issued first; drains under the gate chains)
    f32x4 a4 = __builtin_amdgcn_mfma_f32_16x16x32_bf16(af[0], wfcfr[0], pbfcC, 0, 0, 0);
    #pragma unroll
    for (int kk = 1; kk < 4; ++kk)
      a4 = __builtin_amdgcn_mfma_f32_16x16x32_bf16(af[kk], wfcfr[kk], a4, 0, 0, 0);

    f32x4 acc[4];
    #pragma unroll
    for (int p = 0; p < 4; ++p)
      acc[p] = __builtin_amdgcn_mfma_f32_16x16x32_bf16(af[0], bfr[p][0], biasC[p], 0, 0, 0);
    #pragma unroll
    for (int kk = 1; kk < 4; ++kk){
      #pragma unroll
      for (int p = 0; p < 4; ++p)
        acc[p] = __builtin_amdgcn_mfma_f32_16x16x32_bf16(af[kk], bfr[p][kk], acc[p], 0, 0, 0);
    }

    float pv = a4[0];                        // pred[q][n] (valid n<2)
    float p0 = __shfl(pv, l0, 64);           // pred[q][0]
    float p1 = __shfl(pv, l0 | 1, 64);       // pred[q][1]

    float g0 = acc[0][0] + wih0v[0] * p0 + wih1v[0] * p1;
    float g1 = acc[1][0] + wih0v[1] * p0 + wih1v[1] * p1;
    float g2 = acc[2][0] + wih0v[2] * p0 + wih1v[2] * p1;
    float g3 = acc[3][0] + wih0v[3] * p0 + wih1v[3] * p1;

    float si = sigm(g0), sf = sigm(g1), tg = tnh(g2), so = sigm(g3);
    cc = sf * cc + si * tg;
    float hv = so * tnh(cc);
    h_lds[cur ^ 1][hwofs] = f2bf(hv);

    if (wv == 0 && n < 2)
      pred_lds[q][d * 2 + n] = f2bf(pv);

    __syncthreads();
    cur ^= 1;
  }

  // epilogue: pred_511 from final h (h_lds[cur])
  if (wv == 0){
    const ush* hb = &h_lds[cur][arow];
    bf16x8 af[4];
    #pragma unroll
    for (int kk = 0; kk < 4; ++kk)
      af[kk] = *reinterpret_cast<const bf16x8*>(hb + kk * 32 + q * 8);
    f32x4 a4 = __builtin_amdgcn_mfma_f32_16x16x32_bf16(af[0], wfcfr[0], pbfcC, 0, 0, 0);
    #pragma unroll
    for (int kk = 1; kk < 4; ++kk)
      a4 = __builtin_amdgcn_mfma_f32_16x16x32_bf16(af[kk], wfcfr[kk], a4, 0, 0, 0);
    if (n < 2)
      pred_lds[q][(TDEC - 1) * 2 + n] = f2bf(a4[0]);
  }
  __syncthreads();

  // bulk coalesced output write: 4 rows x 1024 ush per block
  if (!isf32){
    int row = tid >> 7, c = (tid & 127) * 8;  // 512 threads x uint4
    uint4 v = *reinterpret_cast<const uint4*>(&pred_lds[row][c]);
    *reinterpret_cast<uint4*>((ush*)outg + (blk * RB + row) * (TDEC * 2) + c) = v;
  } else {
    for (int i = tid; i < RB * TDEC * 2; i += NTHR){
      int row = i >> 10, c = i & 1023;
      ((float*)outg)[(blk * RB + row) * (TDEC * 2) + c] = bf2f(pred_lds[row][c]);
    }
  }
}

extern "C" void kernel_launch(void* const* d_in, const int* in_sizes, int n_in,
                              void* d_out, int out_size, void* d_ws, size_t ws_size,
                              hipStream_t stream) {
  lstm_kernel<<<dim3(NBLK), dim3(NTHR), 0, stream>>>(
      d_in[0], d_in[1], d_in[2], d_in[3], d_in[4], d_in[5], d_in[6], d_out);
}

// Round 6
// 432.112 us; speedup vs baseline: 2.7651x; 1.0813x over previous
//
#include <hip/hip_runtime.h>

typedef unsigned short ush;
typedef unsigned int uint32;
typedef __attribute__((ext_vector_type(8))) __bf16 bf16x8;
typedef __attribute__((ext_vector_type(4))) float f32x4;

#define NBLK 256
#define RB   4     // batch rows per block
#define NTHR 512
#define SENC 256
#define TDEC 512
#define HDIM 128
#define HSTR 144   // h row stride (ush): 72 dw ≡ 8 mod 32 -> replicated reads/writes 2-way (free)
#define XSTR 520   // x row stride (ush)
#define PSTR 1024  // pred row stride (ush)

#define LOG2E  1.4426950408889634f
#define LOG2E2 2.8853900817779268f

__device__ __forceinline__ float bf2f(ush u){
  uint32 v = ((uint32)u) << 16;
  return __builtin_bit_cast(float, v);
}
__device__ __forceinline__ ush f2bf(float f){            // RNE
  uint32 u = __builtin_bit_cast(uint32, f);
  u = (u + 0x7FFFu + ((u >> 16) & 1u)) >> 16;
  return (ush)u;
}
__device__ __forceinline__ float lo16f(uint32 w){ return __builtin_bit_cast(float, w << 16); }
__device__ __forceinline__ float hi16f(uint32 w){ return __builtin_bit_cast(float, w & 0xFFFF0000u); }

__device__ __forceinline__ float loadf(const void* p, int i, bool f32){
  return f32 ? ((const float*)p)[i] : bf2f(((const ush*)p)[i]);
}
// raw bf16 fragment load: bit-exact copy of harness weights for bf16 inputs
__device__ __forceinline__ bf16x8 load8bf(const void* p, int i, bool f32){
  bf16x8 r;
  if (!f32){
    uint4 u = *reinterpret_cast<const uint4*>((const ush*)p + i);
    r = __builtin_bit_cast(bf16x8, u);
  } else {
    const float* fp = (const float*)p + i;
    #pragma unroll
    for (int j = 0; j < 8; ++j) r[j] = (__bf16)fp[j];
  }
  return r;
}
__device__ __forceinline__ float sigm(float x){
  return __builtin_amdgcn_rcpf(1.0f + __builtin_amdgcn_exp2f(-x * LOG2E));
}
__device__ __forceinline__ float tnh(float x){
  return 1.0f - 2.0f * __builtin_amdgcn_rcpf(__builtin_amdgcn_exp2f(x * LOG2E2) + 1.0f);
}
__device__ __forceinline__ f32x4 mfma4(const bf16x8* af, const bf16x8* b, f32x4 c){
  f32x4 r = __builtin_amdgcn_mfma_f32_16x16x32_bf16(af[0], b[0], c, 0, 0, 0);
  r = __builtin_amdgcn_mfma_f32_16x16x32_bf16(af[1], b[1], r, 0, 0, 0);
  r = __builtin_amdgcn_mfma_f32_16x16x32_bf16(af[2], b[2], r, 0, 0, 0);
  r = __builtin_amdgcn_mfma_f32_16x16x32_bf16(af[3], b[3], r, 0, 0, 0);
  return r;
}

// 256 blocks x 4 batch rows, 8 waves/block; wave w owns hidden cols [16w,16w+16).
// A-ROW REPLICATION: A[m] = h[m>>2] -> C[4q+r][n] = gates[q][n] in every reg;
// lane (n,q) reads acc[0] directly (no selects). Bias rides as the C operand
// of the first MFMA. Pred B-matrix is COLUMN-REPLICATED (B[k][n]=wfc[n&1][k])
// so every lane gets pred[q][n&1] locally; the partner column comes from one
// shfl_xor(.,1); per-lane wa/wb weight swap is precomputed (loop-invariant).
// Gate chains issued i,f,g,o with activations interleaved at distance-1 so
// trans ops never block later MFMA issue (in-order waves). One barrier/step.
__global__ void __launch_bounds__(NTHR, 2)
lstm_kernel(const void* __restrict__ xg,  const void* __restrict__ wih,
            const void* __restrict__ whh, const void* __restrict__ bih,
            const void* __restrict__ bhh, const void* __restrict__ wfc,
            const void* __restrict__ bfc, void* __restrict__ outg)
{
  __shared__ __attribute__((aligned(16))) ush x_lds[RB * XSTR];      // [row][t*2+c]
  __shared__ __attribute__((aligned(16))) ush h_lds[2][RB * HSTR];   // [buf][row][j]
  __shared__ __attribute__((aligned(16))) ush pred_lds[RB][PSTR];    // [row][d*2+o]

  const int tid   = threadIdx.x;
  const int lane  = tid & 63;
  const int wv    = tid >> 6;
  const int n     = lane & 15;   // MFMA col index within tile (= A-row m)
  const int q     = lane >> 4;   // quad; this lane's batch row
  const int gbase = wv << 4;
  const int blk   = blockIdx.x;

  // runtime storage-dtype detection (bf16 vs f32) from w_hh bit patterns
  const uint32* wp = (const uint32*)whh;
  int cnt = 0;
  #pragma unroll
  for (int i = 0; i < 64; ++i){
    uint32 e = (wp[i] >> 7) & 0xFFu;
    cnt += (e >= 90u && e <= 140u) ? 1 : 0;
  }
  const bool isf32 = (cnt < 40);

  for (int i = tid; i < 2 * RB * HSTR; i += NTHR) h_lds[0][i] = 0;  // both bufs

  // stage this block's 4 encoder rows into LDS as bf16: [row][t*2+c]
  if (!isf32){
    if (tid < 256){
      int row = tid >> 6, c = (tid & 63) * 8;
      uint4 v = *reinterpret_cast<const uint4*>((const ush*)xg + (blk * RB + row) * (SENC * 2) + c);
      *reinterpret_cast<uint4*>(&x_lds[row * XSTR + c]) = v;
    }
  } else {
    for (int i = tid; i < RB * SENC * 2; i += NTHR){
      int row = i >> 9, c = i & 511;
      x_lds[row * XSTR + c] = f2bf(((const float*)xg)[(blk * RB + row) * (SENC * 2) + c]);
    }
  }

  // ---- loop-invariant preloads: weights RAW (bit-exact for bf16) ----
  float wih0v[4], wih1v[4];
  f32x4 biasC[4];    // broadcast bias, used as C operand of first MFMA
  bf16x8 bfr[4][4];  // [gate p][kk]: B[k][g]=Whh[g][k], k=kk*32+q*8+j, g=p*128+gbase+n
  #pragma unroll
  for (int p = 0; p < 4; ++p){
    int g = p * 128 + gbase + n;
    float b = loadf(bih, g, isf32) + loadf(bhh, g, isf32);
    biasC[p][0] = b; biasC[p][1] = b; biasC[p][2] = b; biasC[p][3] = b;
    wih0v[p] = loadf(wih, g * 2 + 0, isf32);
    wih1v[p] = loadf(wih, g * 2 + 1, isf32);
    #pragma unroll
    for (int kk = 0; kk < 4; ++kk)
      bfr[p][kk] = load8bf(whh, g * HDIM + kk * 32 + q * 8, isf32);
  }
  // pred tile B-frag, COLUMN-REPLICATED: B[k][n] = wfc[n&1][k]
  bf16x8 wfcfr[4];
  #pragma unroll
  for (int kk = 0; kk < 4; ++kk){
    #pragma unroll
    for (int j = 0; j < 8; ++j){
      int k = kk * 32 + q * 8 + j;
      wfcfr[kk][j] = __builtin_bit_cast(__bf16, f2bf(loadf(wfc, (n & 1) * HDIM + k, isf32)));
    }
  }
  f32x4 pbfcC;
  {
    float pb = loadf(bfc, n & 1, isf32);
    pbfcC[0] = pb; pbfcC[1] = pb; pbfcC[2] = pb; pbfcC[3] = pb;
  }
  // per-lane feedback weights: g += wa*pv + wb*po, pv = pred[q][n&1]
  float wav[4], wbv[4];
  #pragma unroll
  for (int p = 0; p < 4; ++p){
    wav[p] = (n & 1) ? wih1v[p] : wih0v[p];
    wbv[p] = (n & 1) ? wih0v[p] : wih1v[p];
  }

  float cc = 0.0f;                   // c-state for (row q, col gbase+n)
  const int arow  = (n >> 2) * HSTR; // replicated A-row base: A[m]=h[m>>2]
  const int hwofs = q * HSTR + gbase + n;  // this lane's h-write offset
  int cur = 0;

  __syncthreads();

  // ---------------- encoder (+ first decode cell at s==SENC) ----------------
  #pragma unroll 1
  for (int s = 0; s <= SENC; ++s){
    int t = (s < SENC) ? s : SENC - 1;   // s==SENC: inp0 = x[:,-1,:]
    uint32 xw = *reinterpret_cast<const uint32*>(&x_lds[q * XSTR + t * 2]);
    float xa = lo16f(xw), xb = hi16f(xw);

    const ush* hb = &h_lds[cur][arow];
    bf16x8 af[4];
    #pragma unroll
    for (int kk = 0; kk < 4; ++kk)
      af[kk] = *reinterpret_cast<const bf16x8*>(hb + kk * 32 + q * 8);

    f32x4 acc0 = mfma4(af, bfr[0], biasC[0]);
    f32x4 acc1 = mfma4(af, bfr[1], biasC[1]);
    float g0 = acc0[0] + wih0v[0] * xa + wih1v[0] * xb;
    float si = sigm(g0);
    f32x4 acc2 = mfma4(af, bfr[2], biasC[2]);
    float g1 = acc1[0] + wih0v[1] * xa + wih1v[1] * xb;
    float sf = sigm(g1);
    f32x4 acc3 = mfma4(af, bfr[3], biasC[3]);
    float g2 = acc2[0] + wih0v[2] * xa + wih1v[2] * xb;
    float tg = tnh(g2);
    cc = sf * cc + si * tg;
    float th = tnh(cc);
    float g3 = acc3[0] + wih0v[3] * xa + wih1v[3] * xb;
    float so = sigm(g3);
    h_lds[cur ^ 1][hwofs] = f2bf(so * th);

    __syncthreads();
    cur ^= 1;
  }

  // ---------------- decoder: pure h-recurrence + pred feedback --------------
  #pragma unroll 1
  for (int d = 0; d < TDEC - 1; ++d){
    const ush* hb = &h_lds[cur][arow];
    bf16x8 af[4];
    #pragma unroll
    for (int kk = 0; kk < 4; ++kk)
      af[kk] = *reinterpret_cast<const bf16x8*>(hb + kk * 32 + q * 8);

    // pred_d: every lane gets pred[q][n&1] locally (column-replicated B)
    f32x4 a4 = mfma4(af, wfcfr, pbfcC);
    float pv = a4[0];
    float po = __shfl_xor(pv, 1, 64);      // partner column

    f32x4 acc0 = mfma4(af, bfr[0], biasC[0]);
    f32x4 acc1 = mfma4(af, bfr[1], biasC[1]);
    float g0 = acc0[0] + wav[0] * pv + wbv[0] * po;
    float si = sigm(g0);
    f32x4 acc2 = mfma4(af, bfr[2], biasC[2]);
    float g1 = acc1[0] + wav[1] * pv + wbv[1] * po;
    float sf = sigm(g1);
    f32x4 acc3 = mfma4(af, bfr[3], biasC[3]);
    float g2 = acc2[0] + wav[2] * pv + wbv[2] * po;
    float tg = tnh(g2);
    cc = sf * cc + si * tg;
    float th = tnh(cc);
    float g3 = acc3[0] + wav[3] * pv + wbv[3] * po;
    float so = sigm(g3);
    h_lds[cur ^ 1][hwofs] = f2bf(so * th);

    if (wv == 0 && n < 2)
      pred_lds[q][d * 2 + n] = f2bf(pv);   // n&1==n for n<2

    __syncthreads();
    cur ^= 1;
  }

  // epilogue: pred_511 from final h (h_lds[cur])
  if (wv == 0){
    const ush* hb = &h_lds[cur][arow];
    bf16x8 af[4];
    #pragma unroll
    for (int kk = 0; kk < 4; ++kk)
      af[kk] = *reinterpret_cast<const bf16x8*>(hb + kk * 32 + q * 8);
    f32x4 a4 = mfma4(af, wfcfr, pbfcC);
    if (n < 2)
      pred_lds[q][(TDEC - 1) * 2 + n] = f2bf(a4[0]);
  }
  __syncthreads();

  // bulk coalesced output write: 4 rows x 1024 ush per block
  if (!isf32){
    int row = tid >> 7, c = (tid & 127) * 8;  // 512 threads x uint4
    uint4 v = *reinterpret_cast<const uint4*>(&pred_lds[row][c]);
    *reinterpret_cast<uint4*>((ush*)outg + (blk * RB + row) * (TDEC * 2) + c) = v;
  } else {
    for (int i = tid; i < RB * TDEC * 2; i += NTHR){
      int row = i >> 10, c = i & 1023;
      ((float*)outg)[(blk * RB + row) * (TDEC * 2) + c] = bf2f(pred_lds[row][c]);
    }
  }
}

extern "C" void kernel_launch(void* const* d_in, const int* in_sizes, int n_in,
                              void* d_out, int out_size, void* d_ws, size_t ws_size,
                              hipStream_t stream) {
  lstm_kernel<<<dim3(NBLK), dim3(NTHR), 0, stream>>>(
      d_in[0], d_in[1], d_in[2], d_in[3], d_in[4], d_in[5], d_in[6], d_out);
}